// Round 1
// 584.651 us; speedup vs baseline: 1.1541x; 1.1541x over previous
//
#include <hip/hip_runtime.h>
#include <hip/hip_bf16.h>
#include <stdint.h>

// Problem constants
#define TOK    8192      // B*S
#define DIN    4096
#define DOUT   4096
#define NEXP   8
#define RK     16
#define NRANK  128       // NEXP*RK
#define KE     4224      // DIN + NRANK (extended K)
#define SEQB   2048      // S (tokens per batch entry)
#define LSCALE 2.0f      // ALPHA/RANK
#define KSPLIT 4
#define KSLICE (DIN / KSPLIT)   // 1024

typedef __attribute__((ext_vector_type(8))) short bf8_t;   // 8 bf16 = 4 VGPRs
typedef __attribute__((ext_vector_type(4))) float f4_t;

__device__ __forceinline__ void async_copy16(const void* g, void* l) {
  __builtin_amdgcn_global_load_lds((const __attribute__((address_space(1))) void*)g,
                                   (__attribute__((address_space(3))) void*)l,
                                   16, 0, 0);
}

__device__ __forceinline__ ushort f2bf(float f) {
  __hip_bfloat16 h = __float2bfloat16(f);
  return *reinterpret_cast<ushort*>(&h);
}

// ---------- fused conversion kernel (fp32 -> bf16, memory-bound) ----------
#define R0 (TOK * DIN / 8)        // 4,194,304
#define R1 (DOUT * DIN / 8)       // 2,097,152
#define R2 (DOUT * NEXP * 2)      //    65,536
#define R3 (NRANK * DIN / 8)      //    65,536
#define RTOT (R0 + R1 + R2 + R3)  // 6,422,528  (= 25088 * 256)

__global__ __launch_bounds__(256)
void cvt_all_kernel(const float* __restrict__ x, const float* __restrict__ wb,
                    const float* __restrict__ lu, const float* __restrict__ ld,
                    ushort* __restrict__ Xe, ushort* __restrict__ Wc,
                    ushort* __restrict__ Ldb) {
  int i = blockIdx.x * 256 + threadIdx.x;
  const float* src;
  ushort* dst;
  if (i < R0) {
    int t = i >> 9;                    // DIN/8 = 512
    int c = (i & 511) * 8;
    src = x + (size_t)t * DIN + c;
    dst = Xe + (size_t)t * KE + c;
  } else if (i < R0 + R1) {
    int j = i - R0;
    int t = j >> 9;
    int c = (j & 511) * 8;
    src = wb + (size_t)t * DIN + c;
    dst = Wc + (size_t)t * KE + c;
  } else if (i < R0 + R1 + R2) {
    int j = i - (R0 + R1);
    int o = j >> 4;
    int rem = j & 15;
    int n = rem >> 1;
    int half = rem & 1;
    src = lu + ((size_t)n * DOUT + o) * RK + half * 8;
    dst = Wc + (size_t)o * KE + DIN + n * RK + half * 8;
  } else {
    int j = i - (R0 + R1 + R2);
    src = ld + (size_t)j * 8;
    dst = Ldb + (size_t)j * 8;
  }
  const float4* s = reinterpret_cast<const float4*>(src);
  float4 a = s[0], b = s[1];
  union { ushort u[8]; uint4 v; } o;
  o.u[0]=f2bf(a.x); o.u[1]=f2bf(a.y); o.u[2]=f2bf(a.z); o.u[3]=f2bf(a.w);
  o.u[4]=f2bf(b.x); o.u[5]=f2bf(b.y); o.u[6]=f2bf(b.z); o.u[7]=f2bf(b.w);
  *reinterpret_cast<uint4*>(dst) = o.v;
}

// ---------- 128x128 bf16 MFMA GEMM (m97 structure) — used for the small
// down-projection GEMM only (MODE 1, split-K) ----------
template<int KLEN, int LDB, int MODE>
__global__ __launch_bounds__(256)
void gemm128(const ushort* __restrict__ A,
             const ushort* __restrict__ Bm,
             float* __restrict__ C) {
  __shared__ __align__(16) ushort As[128 * 32];
  __shared__ __align__(16) ushort Bs[128 * 32];

  const int tid  = threadIdx.x;
  const int wave = tid >> 6;
  const int lane = tid & 63;

  int bm, bn;
  if (MODE == 0) {
    int bid = blockIdx.x;
    int xcd = bid & 7;
    int idx = bid >> 3;
    int nt  = xcd * 4 + (idx & 3);
    int mt  = idx >> 2;
    bm = mt * 128;
    bn = nt * 128;
  } else {
    bm = blockIdx.y * 128;
    bn = blockIdx.x * 128;
  }
  const int wm = wave & 1, wn = wave >> 1;

  f4_t acc[4][4];
#pragma unroll
  for (int i = 0; i < 4; i++)
#pragma unroll
    for (int j = 0; j < 4; j++) acc[i][j] = (f4_t){0.f, 0.f, 0.f, 0.f};

  const int f0 = tid * 8;
  const int r0 = f0 >> 5, c0 = f0 & 31;
  const int f1 = (256 + tid) * 8;
  const int r1 = f1 >> 5, c1 = f1 & 31;
  const int l0 = (wave << 6) * 8;
  const int l1 = (256 + (wave << 6)) * 8;

  const ushort* Ar = As + (wm * 64 + (lane & 15)) * 32 + (lane >> 4) * 8;
  const ushort* Br = Bs + (wn * 64 + (lane & 15)) * 32 + (lane >> 4) * 8;

  const int kbase = (MODE == 1) ? blockIdx.z * KSLICE : 0;
  const int kend  = kbase + KLEN;

  for (int k0 = kbase; k0 < kend; k0 += 32) {
    __syncthreads();
    async_copy16(A  + (size_t)(bm + r0) * KE  + k0 + c0, (void*)(As + l0));
    async_copy16(A  + (size_t)(bm + r1) * KE  + k0 + c1, (void*)(As + l1));
    async_copy16(Bm + (size_t)(bn + r0) * LDB + k0 + c0, (void*)(Bs + l0));
    async_copy16(Bm + (size_t)(bn + r1) * LDB + k0 + c1, (void*)(Bs + l1));
    __syncthreads();
    bf8_t av[4], bv[4];
#pragma unroll
    for (int i = 0; i < 4; i++) av[i] = *(const bf8_t*)(Ar + i * 16 * 32);
#pragma unroll
    for (int j = 0; j < 4; j++) bv[j] = *(const bf8_t*)(Br + j * 16 * 32);
#pragma unroll
    for (int i = 0; i < 4; i++)
#pragma unroll
      for (int j = 0; j < 4; j++)
        acc[i][j] = __builtin_amdgcn_mfma_f32_16x16x32_bf16(av[i], bv[j], acc[i][j], 0, 0, 0);
  }

  if (MODE == 0) {
#pragma unroll
    for (int i = 0; i < 4; i++) {
      int row = bm + wm * 64 + i * 16 + (lane >> 4) * 4;
#pragma unroll
      for (int j = 0; j < 4; j++) {
        int col = bn + wn * 64 + j * 16 + (lane & 15);
#pragma unroll
        for (int rr = 0; rr < 4; rr++)
          C[(size_t)(row + rr) * DOUT + col] = acc[i][j][rr];
      }
    }
  } else {
    float* Dz = C + (size_t)blockIdx.z * TOK * NRANK;
#pragma unroll
    for (int i = 0; i < 4; i++) {
      int row = bm + wm * 64 + i * 16 + (lane >> 4) * 4;
#pragma unroll
      for (int j = 0; j < 4; j++) {
        int col = wn * 64 + j * 16 + (lane & 15);
#pragma unroll
        for (int rr = 0; rr < 4; rr++)
          Dz[(size_t)(row + rr) * NRANK + col] = acc[i][j][rr];
      }
    }
  }
}

// reduce split-K slices, scale by routing*LSCALE, pack bf16 into Xe extension cols
__global__ void scale_store_kernel(const float* __restrict__ D32,
                                   const float* __restrict__ rw,
                                   ushort* __restrict__ Xe) {
  int i = blockIdx.x * 256 + threadIdx.x;          // [0, TOK*NRANK/4)
  int t = i >> 5;                                  // token
  int g = (i & 31) * 4;                            // col base (4 cols, same expert)
  size_t base = (size_t)t * NRANK + g;
  const size_t ss = (size_t)TOK * NRANK;
  float4 a = *reinterpret_cast<const float4*>(D32 + base);
  float4 b = *reinterpret_cast<const float4*>(D32 + ss + base);
  float4 c = *reinterpret_cast<const float4*>(D32 + 2 * ss + base);
  float4 d = *reinterpret_cast<const float4*>(D32 + 3 * ss + base);
  int n = g >> 4;                                  // expert index
  int bb = t / SEQB;
  float s = rw[bb * NEXP + n] * LSCALE;
  union { ushort u[4]; uint2 v; } o;
  o.u[0] = f2bf((a.x + b.x + c.x + d.x) * s);
  o.u[1] = f2bf((a.y + b.y + c.y + d.y) * s);
  o.u[2] = f2bf((a.z + b.z + c.z + d.z) * s);
  o.u[3] = f2bf((a.w + b.w + c.w + d.w) * s);
  *reinterpret_cast<uint2*>(Xe + (size_t)t * KE + DIN + g) = o.v;
}

// ---------- 256x256 8-phase bf16 GEMM (m201-style schedule, plain HIP) ----------
// C[m,n] = sum_k A[m,k]*B[n,k], A:[TOK,KE], B:[DOUT,KE] (B^T layout), fp32 out.
// Structure: BK=32 K-tiles; 4-deep LDS ring buffer (compute tile T from buf[T&3]
// while staging tile T+3 into buf[(T+3)&3] -> producer/consumer buffers always
// disjoint, no intra-tile WAR hazards). Two phases per tile, each phase:
//   {ds_read 4-or-8 frags | issue 2 global_load_lds} -> s_barrier ->
//   lgkmcnt(0) -> setprio(1) 16x MFMA setprio(0) -> s_barrier
// Counted s_waitcnt vmcnt(8) once per tile (2 tiles of loads stay in flight
// across barriers; never drains to 0 in steady state).
// LDS XOR-swizzle: physical byte addr = logical ^ ((logical>>7)&7)<<4
// (involution; rows spread across bank groups: 8-way conflict -> 2-way=free).
// Staged via pre-swizzled per-lane GLOBAL source + linear global_load_lds dest;
// ds_read applies the same XOR (collapses to a per-thread constant col offset).
#define BK32  32
#define NT132 (KE / BK32)    // 132

__global__ __launch_bounds__(512, 2)
void gemm256(const ushort* __restrict__ A, const ushort* __restrict__ Bm,
             float* __restrict__ C) {
  __shared__ __align__(16) ushort As[4][256 * 32];   // 64 KiB
  __shared__ __align__(16) ushort Bs[4][256 * 32];   // 64 KiB

  const int tid  = threadIdx.x;
  const int w    = tid >> 6;        // wave 0..7
  const int lane = tid & 63;
  const int wm   = w >> 2;          // 0..1  (M half)
  const int wn   = w & 3;           // 0..3  (N quarter)

  // XCD-bijective swizzle over 512 blocks (512 % 8 == 0): each XCD gets a
  // contiguous chunk of 64 = two full 256-col B panels (~4.3MB ~ its L2),
  // swept over all 32 m-tiles; A streams through shared L3.
  const int bid = blockIdx.x;
  const int swz = (bid & 7) * 64 + (bid >> 3);
  const int bm  = (swz & 31) * 256;
  const int bn  = (swz >> 5) * 256;

  f4_t acc[8][4];
#pragma unroll
  for (int i = 0; i < 8; ++i)
#pragma unroll
    for (int j = 0; j < 4; ++j) acc[i][j] = (f4_t){0.f, 0.f, 0.f, 0.f};

  // ---- frag-read geometry ----
  // MFMA 16x16x32 A/B frag: lane holds [row = lane&15][k = (lane>>4)*8 .. +8].
  // logical byte addr in tile = row*64 + (lane>>4)*16; swizzle XOR value
  // ((addr>>7)&7)<<4 reduces to ((lane&15)>>1)<<4 (frag base rows are even
  // multiples of 16) -> per-thread constant swizzled column offset:
  const int frow = lane & 15;
  const int cbs  = (((lane >> 4) ^ (frow >> 1)) << 4);
  const int ar0  = wm * 128;        // wave's A row base (rows)
  const int br0  = wn * 64;         // wave's B row base (rows)

  // ---- staging geometry (per-thread, tile = 256x32 bf16 = 16 KiB) ----
  // dest slots (linear, wave-uniform base + lane*16):
  //   r=0: bytes [w*1024, +1024) ; r=1: +8192. Source is pre-swizzled:
  //   logical = slot ^ ((slot>>7)&7)<<4, and (slot>>7)&7 == lane>>3.
  const int sxr = (lane >> 3) << 4;
  const int t0  = (w << 10) + (lane << 4);
  const int l0b = t0 ^ sxr;
  const int l1b = (t0 + 8192) ^ sxr;
  const size_t goff0 = (size_t)(l0b >> 6) * KE + ((l0b & 63) >> 1); // elements
  const size_t goff1 = (size_t)(l1b >> 6) * KE + ((l1b & 63) >> 1);
  const int ld0 = (w << 9);          // LDS dest base, elements
  const int ld1 = (w << 9) + 4096;

  const ushort* Ap = A  + (size_t)bm * KE;
  const ushort* Bp = Bm + (size_t)bn * KE;

#define STAGE_A256(kt, buf) do {                                   \
    const ushort* cp_ = Ap + (size_t)(kt) * BK32;                  \
    async_copy16(cp_ + goff0, (void*)(As[buf] + ld0));             \
    async_copy16(cp_ + goff1, (void*)(As[buf] + ld1));             \
  } while (0)
#define STAGE_B256(kt, buf) do {                                   \
    const ushort* cp_ = Bp + (size_t)(kt) * BK32;                  \
    async_copy16(cp_ + goff0, (void*)(Bs[buf] + ld0));             \
    async_copy16(cp_ + goff1, (void*)(Bs[buf] + ld1));             \
  } while (0)

  // prologue: stage tiles 0,1,2 into ring slots 0,1,2 (12 loads/thread).
  STAGE_A256(0, 0); STAGE_B256(0, 0);
  STAGE_A256(1, 1); STAGE_B256(1, 1);
  STAGE_A256(2, 2); STAGE_B256(2, 2);
  asm volatile("s_waitcnt vmcnt(8)" ::: "memory");   // tile 0 landed; 1,2 in flight
  __builtin_amdgcn_s_barrier();

  for (int T = 0; T < NT132; ++T) {
    const int b  = T & 3;
    const int sb = (T + 3) & 3;
    const char* Ab = (const char*)As[b];
    const char* Bb = (const char*)Bs[b];
    bf8_t a0[4], a1[4], bv[4];

    // ---- phase 0: read A(mq=0) 4 + B 4 frags; stage A-tile T+3; MFMA mq=0 ----
#pragma unroll
    for (int f = 0; f < 4; ++f)
      a0[f] = *(const bf8_t*)(Ab + (((ar0 + f * 16 + frow) << 6) ^ cbs));
#pragma unroll
    for (int g = 0; g < 4; ++g)
      bv[g] = *(const bf8_t*)(Bb + (((br0 + g * 16 + frow) << 6) ^ cbs));
    if (T + 3 < NT132) STAGE_A256(T + 3, sb);
    __builtin_amdgcn_s_barrier();
    asm volatile("s_waitcnt lgkmcnt(0)" ::: "memory");
    __builtin_amdgcn_sched_barrier(0);
    __builtin_amdgcn_s_setprio(1);
#pragma unroll
    for (int f = 0; f < 4; ++f)
#pragma unroll
      for (int g = 0; g < 4; ++g)
        acc[f][g] = __builtin_amdgcn_mfma_f32_16x16x32_bf16(a0[f], bv[g], acc[f][g], 0, 0, 0);
    __builtin_amdgcn_s_setprio(0);
    __builtin_amdgcn_s_barrier();

    // ---- phase 1: read A(mq=1) 4 frags; stage B-tile T+3; MFMA mq=1 ----
#pragma unroll
    for (int f = 0; f < 4; ++f)
      a1[f] = *(const bf8_t*)(Ab + (((ar0 + 64 + f * 16 + frow) << 6) ^ cbs));
    if (T + 3 < NT132) STAGE_B256(T + 3, sb);
    __builtin_amdgcn_s_barrier();
    asm volatile("s_waitcnt lgkmcnt(0)" ::: "memory");
    __builtin_amdgcn_sched_barrier(0);
    __builtin_amdgcn_s_setprio(1);
#pragma unroll
    for (int f = 0; f < 4; ++f)
#pragma unroll
      for (int g = 0; g < 4; ++g)
        acc[4 + f][g] = __builtin_amdgcn_mfma_f32_16x16x32_bf16(a1[f], bv[g], acc[4 + f][g], 0, 0, 0);
    __builtin_amdgcn_s_setprio(0);
    // counted vmcnt once per tile: keep the 8 newest loads (tiles T+2, T+3)
    // in flight; guarantees tile T+1 is fully in LDS before its phase-0 reads.
    if (T < NT132 - 3)       asm volatile("s_waitcnt vmcnt(8)" ::: "memory");
    else if (T == NT132 - 3) asm volatile("s_waitcnt vmcnt(4)" ::: "memory");
    else if (T == NT132 - 2) asm volatile("s_waitcnt vmcnt(0)" ::: "memory");
    __builtin_amdgcn_s_barrier();
  }

  // epilogue: fp32 C write (C/D layout: col = lane&15, row = (lane>>4)*4 + rr)
#pragma unroll
  for (int i = 0; i < 8; ++i) {
    int row = bm + wm * 128 + i * 16 + (lane >> 4) * 4;
#pragma unroll
    for (int j = 0; j < 4; ++j) {
      int col = bn + wn * 64 + j * 16 + (lane & 15);
#pragma unroll
      for (int rr = 0; rr < 4; ++rr)
        C[(size_t)(row + rr) * DOUT + col] = acc[i][j][rr];
    }
  }
#undef STAGE_A256
#undef STAGE_B256
}

extern "C" void kernel_launch(void* const* d_in, const int* in_sizes, int n_in,
                              void* d_out, int out_size, void* d_ws, size_t ws_size,
                              hipStream_t stream) {
  const float* x  = (const float*)d_in[0];
  const float* rw = (const float*)d_in[1];
  const float* wb = (const float*)d_in[2];
  const float* ld = (const float*)d_in[3];
  const float* lu = (const float*)d_in[4];
  float* out = (float*)d_out;

  // workspace layout (bf16 elements unless noted)
  ushort* Xe  = (ushort*)d_ws;                         // TOK*KE
  ushort* Wc  = Xe + (size_t)TOK * KE;                 // DOUT*KE
  ushort* Ldb = Wc + (size_t)DOUT * KE;                // NRANK*DIN
  float*  D32 = (float*)(Ldb + (size_t)NRANK * DIN);   // KSPLIT*TOK*NRANK fp32

  // one fused conversion dispatch (x, W_base, lora_up, lora_down -> bf16)
  cvt_all_kernel<<<RTOT / 256, 256, 0, stream>>>(x, wb, lu, ld, Xe, Wc, Ldb);

  // down-projection: D32[z] = Xe[:, z*1024:(z+1)*1024] @ Ld^T   (split-K)
  gemm128<KSLICE, DIN, 1><<<dim3(1, TOK / 128, KSPLIT), 256, 0, stream>>>(Xe, Ldb, D32);
  // reduce + routing scale + pack into Xe extension columns
  scale_store_kernel<<<TOK * NRANK / 4 / 256, 256, 0, stream>>>(D32, rw, Xe);
  // main GEMM: out = Xe[TOK,KE] @ Wc[DOUT,KE]^T  (256x256 8-phase schedule)
  gemm256<<<dim3((TOK / 256) * (DOUT / 256)), 512, 0, stream>>>(Xe, Wc, out);
}

// Round 2
// 584.202 us; speedup vs baseline: 1.1550x; 1.0008x over previous
//
#include <hip/hip_runtime.h>
#include <hip/hip_bf16.h>
#include <stdint.h>

// Problem constants
#define TOK    8192      // B*S
#define DIN    4096
#define DOUT   4096
#define NEXP   8
#define RK     16
#define NRANK  128       // NEXP*RK
#define KE     4224      // DIN + NRANK (extended K)
#define SEQB   2048      // S (tokens per batch entry)
#define LSCALE 2.0f      // ALPHA/RANK
#define KSPLIT 4
#define KSLICE (DIN / KSPLIT)   // 1024

typedef __attribute__((ext_vector_type(8))) short bf8_t;   // 8 bf16 = 4 VGPRs
typedef __attribute__((ext_vector_type(4))) float f4_t;

__device__ __forceinline__ void async_copy16(const void* g, void* l) {
  __builtin_amdgcn_global_load_lds((const __attribute__((address_space(1))) void*)g,
                                   (__attribute__((address_space(3))) void*)l,
                                   16, 0, 0);
}

__device__ __forceinline__ ushort f2bf(float f) {
  __hip_bfloat16 h = __float2bfloat16(f);
  return *reinterpret_cast<ushort*>(&h);
}

// ---------- fused conversion kernel (fp32 -> bf16, memory-bound) ----------
#define R0 (TOK * DIN / 8)        // 4,194,304
#define R1 (DOUT * DIN / 8)       // 2,097,152
#define R2 (DOUT * NEXP * 2)      //    65,536
#define R3 (NRANK * DIN / 8)      //    65,536
#define RTOT (R0 + R1 + R2 + R3)  // 6,422,528  (= 25088 * 256)

__global__ __launch_bounds__(256)
void cvt_all_kernel(const float* __restrict__ x, const float* __restrict__ wb,
                    const float* __restrict__ lu, const float* __restrict__ ld,
                    ushort* __restrict__ Xe, ushort* __restrict__ Wc,
                    ushort* __restrict__ Ldb) {
  int i = blockIdx.x * 256 + threadIdx.x;
  const float* src;
  ushort* dst;
  if (i < R0) {
    int t = i >> 9;                    // DIN/8 = 512
    int c = (i & 511) * 8;
    src = x + (size_t)t * DIN + c;
    dst = Xe + (size_t)t * KE + c;
  } else if (i < R0 + R1) {
    int j = i - R0;
    int t = j >> 9;
    int c = (j & 511) * 8;
    src = wb + (size_t)t * DIN + c;
    dst = Wc + (size_t)t * KE + c;
  } else if (i < R0 + R1 + R2) {
    int j = i - (R0 + R1);
    int o = j >> 4;
    int rem = j & 15;
    int n = rem >> 1;
    int half = rem & 1;
    src = lu + ((size_t)n * DOUT + o) * RK + half * 8;
    dst = Wc + (size_t)o * KE + DIN + n * RK + half * 8;
  } else {
    int j = i - (R0 + R1 + R2);
    src = ld + (size_t)j * 8;
    dst = Ldb + (size_t)j * 8;
  }
  const float4* s = reinterpret_cast<const float4*>(src);
  float4 a = s[0], b = s[1];
  union { ushort u[8]; uint4 v; } o;
  o.u[0]=f2bf(a.x); o.u[1]=f2bf(a.y); o.u[2]=f2bf(a.z); o.u[3]=f2bf(a.w);
  o.u[4]=f2bf(b.x); o.u[5]=f2bf(b.y); o.u[6]=f2bf(b.z); o.u[7]=f2bf(b.w);
  *reinterpret_cast<uint4*>(dst) = o.v;
}

// ---------- 128x128 bf16 MFMA GEMM (m97 structure) — down-projection only ----------
template<int KLEN, int LDB, int MODE>
__global__ __launch_bounds__(256)
void gemm128(const ushort* __restrict__ A,
             const ushort* __restrict__ Bm,
             float* __restrict__ C) {
  __shared__ __align__(16) ushort As[128 * 32];
  __shared__ __align__(16) ushort Bs[128 * 32];

  const int tid  = threadIdx.x;
  const int wave = tid >> 6;
  const int lane = tid & 63;

  int bm, bn;
  if (MODE == 0) {
    int bid = blockIdx.x;
    int xcd = bid & 7;
    int idx = bid >> 3;
    int nt  = xcd * 4 + (idx & 3);
    int mt  = idx >> 2;
    bm = mt * 128;
    bn = nt * 128;
  } else {
    bm = blockIdx.y * 128;
    bn = blockIdx.x * 128;
  }
  const int wm = wave & 1, wn = wave >> 1;

  f4_t acc[4][4];
#pragma unroll
  for (int i = 0; i < 4; i++)
#pragma unroll
    for (int j = 0; j < 4; j++) acc[i][j] = (f4_t){0.f, 0.f, 0.f, 0.f};

  const int f0 = tid * 8;
  const int r0 = f0 >> 5, c0 = f0 & 31;
  const int f1 = (256 + tid) * 8;
  const int r1 = f1 >> 5, c1 = f1 & 31;
  const int l0 = (wave << 6) * 8;
  const int l1 = (256 + (wave << 6)) * 8;

  const ushort* Ar = As + (wm * 64 + (lane & 15)) * 32 + (lane >> 4) * 8;
  const ushort* Br = Bs + (wn * 64 + (lane & 15)) * 32 + (lane >> 4) * 8;

  const int kbase = (MODE == 1) ? blockIdx.z * KSLICE : 0;
  const int kend  = kbase + KLEN;

  for (int k0 = kbase; k0 < kend; k0 += 32) {
    __syncthreads();
    async_copy16(A  + (size_t)(bm + r0) * KE  + k0 + c0, (void*)(As + l0));
    async_copy16(A  + (size_t)(bm + r1) * KE  + k0 + c1, (void*)(As + l1));
    async_copy16(Bm + (size_t)(bn + r0) * LDB + k0 + c0, (void*)(Bs + l0));
    async_copy16(Bm + (size_t)(bn + r1) * LDB + k0 + c1, (void*)(Bs + l1));
    __syncthreads();
    bf8_t av[4], bv[4];
#pragma unroll
    for (int i = 0; i < 4; i++) av[i] = *(const bf8_t*)(Ar + i * 16 * 32);
#pragma unroll
    for (int j = 0; j < 4; j++) bv[j] = *(const bf8_t*)(Br + j * 16 * 32);
#pragma unroll
    for (int i = 0; i < 4; i++)
#pragma unroll
      for (int j = 0; j < 4; j++)
        acc[i][j] = __builtin_amdgcn_mfma_f32_16x16x32_bf16(av[i], bv[j], acc[i][j], 0, 0, 0);
  }

  if (MODE == 0) {
#pragma unroll
    for (int i = 0; i < 4; i++) {
      int row = bm + wm * 64 + i * 16 + (lane >> 4) * 4;
#pragma unroll
      for (int j = 0; j < 4; j++) {
        int col = bn + wn * 64 + j * 16 + (lane & 15);
#pragma unroll
        for (int rr = 0; rr < 4; rr++)
          C[(size_t)(row + rr) * DOUT + col] = acc[i][j][rr];
      }
    }
  } else {
    float* Dz = C + (size_t)blockIdx.z * TOK * NRANK;
#pragma unroll
    for (int i = 0; i < 4; i++) {
      int row = bm + wm * 64 + i * 16 + (lane >> 4) * 4;
#pragma unroll
      for (int j = 0; j < 4; j++) {
        int col = wn * 64 + j * 16 + (lane & 15);
#pragma unroll
        for (int rr = 0; rr < 4; rr++)
          Dz[(size_t)(row + rr) * NRANK + col] = acc[i][j][rr];
      }
    }
  }
}

// reduce split-K slices, scale by routing*LSCALE, pack bf16 into Xe extension cols
__global__ void scale_store_kernel(const float* __restrict__ D32,
                                   const float* __restrict__ rw,
                                   ushort* __restrict__ Xe) {
  int i = blockIdx.x * 256 + threadIdx.x;          // [0, TOK*NRANK/4)
  int t = i >> 5;                                  // token
  int g = (i & 31) * 4;                            // col base (4 cols, same expert)
  size_t base = (size_t)t * NRANK + g;
  const size_t ss = (size_t)TOK * NRANK;
  float4 a = *reinterpret_cast<const float4*>(D32 + base);
  float4 b = *reinterpret_cast<const float4*>(D32 + ss + base);
  float4 c = *reinterpret_cast<const float4*>(D32 + 2 * ss + base);
  float4 d = *reinterpret_cast<const float4*>(D32 + 3 * ss + base);
  int n = g >> 4;                                  // expert index
  int bb = t / SEQB;
  float s = rw[bb * NEXP + n] * LSCALE;
  union { ushort u[4]; uint2 v; } o;
  o.u[0] = f2bf((a.x + b.x + c.x + d.x) * s);
  o.u[1] = f2bf((a.y + b.y + c.y + d.y) * s);
  o.u[2] = f2bf((a.z + b.z + c.z + d.z) * s);
  o.u[3] = f2bf((a.w + b.w + c.w + d.w) * s);
  *reinterpret_cast<uint2*>(Xe + (size_t)t * KE + DIN + g) = o.v;
}

// ---------- 256x256 bf16 GEMM, m201-style schedule (plain HIP) ----------
// C[m,n] = sum_k A[m,k]*B[n,k], A:[TOK,KE], B:[DOUT,KE] (B^T layout), fp32 out.
// BK=32 K-tiles; 4-slot LDS ring, prefetch depth 2 (compute T, T+1 staged,
// T+2 staging) -> <=8 global_load_lds in flight per wave; counted vmcnt(4)
// once per tile (never 0 in steady state).
// Per tile, 2 phases each {barrier -> setprio(1) 16 MFMA setprio(0) -> barrier};
// ALL 12 ds_read_b128 issue at tile top so the compiler's counted lgkmcnt lets
// phase-0 MFMAs overlap phase-1's reads (no manual lgkm drain, no sched_barrier
// -- m141: order-pinning cost -42%; m97: compiler lgkm insertion near-optimal).
// LDS XOR-swizzle (proven round 1: SQ_LDS_BANK_CONFLICT = 0): physical byte =
// logical ^ ((logical>>7)&7)<<4, staged via pre-swizzled per-lane global source
// + linear global_load_lds dest; ds_read applies the same XOR (collapses to a
// per-thread constant column offset).
#define BK32  32
#define NT132 (KE / BK32)    // 132

__global__ __launch_bounds__(512, 2)
void gemm256(const ushort* __restrict__ A, const ushort* __restrict__ Bm,
             float* __restrict__ C) {
  __shared__ __align__(16) ushort As[4][256 * 32];   // 64 KiB
  __shared__ __align__(16) ushort Bs[4][256 * 32];   // 64 KiB

  const int tid  = threadIdx.x;
  const int w    = tid >> 6;        // wave 0..7
  const int lane = tid & 63;
  const int wm   = w >> 2;          // 0..1  (M half)
  const int wn   = w & 3;           // 0..3  (N quarter)

  // XCD-aware rectangular chunks: grid = 32 m-tiles x 16 n-tiles = 512 blocks.
  // XCD x (= bid&7) owns an 8m x 8n sub-rectangle; its 32 concurrent blocks
  // (round 1) span 8 m-panels x 4 n-panels -> each A panel shared by 4 CUs,
  // each B panel by 8 CUs within one L2 (round-1 FETCH ~26MB/XCD vs 71MB for
  // the 32m x 1n mapping measured at 557MB total). Bijective: (x&3) m-group,
  // (x>>2) n-group, j=bid>>3 -> (j&7, j>>3).
  const int bid = blockIdx.x;
  const int xg  = bid & 7;
  const int j   = bid >> 3;                       // 0..63
  const int bm  = (((xg & 3) << 3) + (j & 7)) << 8;   // mi*256, mi 0..31
  const int bn  = (((xg >> 2) << 3) + (j >> 3)) << 8; // ni*256, ni 0..15

  f4_t acc[8][4];
#pragma unroll
  for (int i = 0; i < 8; ++i)
#pragma unroll
    for (int jj = 0; jj < 4; ++jj) acc[i][jj] = (f4_t){0.f, 0.f, 0.f, 0.f};

  // ---- frag-read geometry (swizzled) ----
  const int frow = lane & 15;
  const int cbs  = (((lane >> 4) ^ (frow >> 1)) << 4);
  const int ar0  = wm * 128;        // wave's A row base (rows)
  const int br0  = wn * 64;         // wave's B row base (rows)

  // ---- staging geometry (per-thread, tile = 256x32 bf16 = 16 KiB) ----
  const int sxr = (lane >> 3) << 4;
  const int t0  = (w << 10) + (lane << 4);
  const int l0b = t0 ^ sxr;
  const int l1b = (t0 + 8192) ^ sxr;
  const size_t goff0 = (size_t)(l0b >> 6) * KE + ((l0b & 63) >> 1); // elements
  const size_t goff1 = (size_t)(l1b >> 6) * KE + ((l1b & 63) >> 1);
  const int ld0 = (w << 9);          // LDS dest base, elements
  const int ld1 = (w << 9) + 4096;

  const ushort* Ap = A  + (size_t)bm * KE;
  const ushort* Bp = Bm + (size_t)bn * KE;

#define STAGE_A256(kt, buf) do {                                   \
    const ushort* cp_ = Ap + (size_t)(kt) * BK32;                  \
    async_copy16(cp_ + goff0, (void*)(As[buf] + ld0));             \
    async_copy16(cp_ + goff1, (void*)(As[buf] + ld1));             \
  } while (0)
#define STAGE_B256(kt, buf) do {                                   \
    const ushort* cp_ = Bp + (size_t)(kt) * BK32;                  \
    async_copy16(cp_ + goff0, (void*)(Bs[buf] + ld0));             \
    async_copy16(cp_ + goff1, (void*)(Bs[buf] + ld1));             \
  } while (0)

  // prologue: stage tiles 0,1 into ring slots 0,1 (8 loads/thread in flight).
  STAGE_A256(0, 0); STAGE_B256(0, 0);
  STAGE_A256(1, 1); STAGE_B256(1, 1);
  asm volatile("s_waitcnt vmcnt(4)" ::: "memory");   // tile 0 landed; 1 in flight
  __builtin_amdgcn_s_barrier();

  for (int T = 0; T < NT132; ++T) {
    const int b  = T & 3;
    const int sb = (T + 2) & 3;
    const char* Ab = (const char*)As[b];
    const char* Bb = (const char*)Bs[b];
    bf8_t a0[4], a1[4], bv[4];

    // ---- all 12 ds_reads for this tile up front; compiler inserts counted
    //      lgkmcnt so phase-0 MFMAs run while a1's reads are still in flight.
#pragma unroll
    for (int f = 0; f < 4; ++f)
      a0[f] = *(const bf8_t*)(Ab + (((ar0 + f * 16 + frow) << 6) ^ cbs));
#pragma unroll
    for (int g = 0; g < 4; ++g)
      bv[g] = *(const bf8_t*)(Bb + (((br0 + g * 16 + frow) << 6) ^ cbs));
#pragma unroll
    for (int f = 0; f < 4; ++f)
      a1[f] = *(const bf8_t*)(Ab + (((ar0 + 64 + f * 16 + frow) << 6) ^ cbs));
    if (T + 2 < NT132) STAGE_A256(T + 2, sb);
    __builtin_amdgcn_s_barrier();

    // ---- phase 0: MFMA M-half 0 ----
    __builtin_amdgcn_s_setprio(1);
#pragma unroll
    for (int f = 0; f < 4; ++f)
#pragma unroll
      for (int g = 0; g < 4; ++g)
        acc[f][g] = __builtin_amdgcn_mfma_f32_16x16x32_bf16(a0[f], bv[g], acc[f][g], 0, 0, 0);
    __builtin_amdgcn_s_setprio(0);
    __builtin_amdgcn_s_barrier();

    // ---- phase 1: MFMA M-half 1 ----
    if (T + 2 < NT132) STAGE_B256(T + 2, sb);
    __builtin_amdgcn_s_barrier();
    __builtin_amdgcn_s_setprio(1);
#pragma unroll
    for (int f = 0; f < 4; ++f)
#pragma unroll
      for (int g = 0; g < 4; ++g)
        acc[4 + f][g] = __builtin_amdgcn_mfma_f32_16x16x32_bf16(a1[f], bv[g], acc[4 + f][g], 0, 0, 0);
    __builtin_amdgcn_s_setprio(0);
    // counted vmcnt once per tile: drain tile T+1's 4 loads, keep T+2's 4
    // in flight; guarantees (with the barrier) tile T+1 fully staged.
    if (T < NT132 - 2)       asm volatile("s_waitcnt vmcnt(4)" ::: "memory");
    else if (T == NT132 - 2) asm volatile("s_waitcnt vmcnt(0)" ::: "memory");
    __builtin_amdgcn_s_barrier();
  }

  // epilogue: fp32 C write (C/D layout: col = lane&15, row = (lane>>4)*4 + rr)
#pragma unroll
  for (int i = 0; i < 8; ++i) {
    int row = bm + wm * 128 + i * 16 + (lane >> 4) * 4;
#pragma unroll
    for (int jj = 0; jj < 4; ++jj) {
      int col = bn + wn * 64 + jj * 16 + (lane & 15);
#pragma unroll
      for (int rr = 0; rr < 4; ++rr)
        C[(size_t)(row + rr) * DOUT + col] = acc[i][jj][rr];
    }
  }
#undef STAGE_A256
#undef STAGE_B256
}

extern "C" void kernel_launch(void* const* d_in, const int* in_sizes, int n_in,
                              void* d_out, int out_size, void* d_ws, size_t ws_size,
                              hipStream_t stream) {
  const float* x  = (const float*)d_in[0];
  const float* rw = (const float*)d_in[1];
  const float* wb = (const float*)d_in[2];
  const float* ld = (const float*)d_in[3];
  const float* lu = (const float*)d_in[4];
  float* out = (float*)d_out;

  // workspace layout (bf16 elements unless noted)
  ushort* Xe  = (ushort*)d_ws;                         // TOK*KE
  ushort* Wc  = Xe + (size_t)TOK * KE;                 // DOUT*KE
  ushort* Ldb = Wc + (size_t)DOUT * KE;                // NRANK*DIN
  float*  D32 = (float*)(Ldb + (size_t)NRANK * DIN);   // KSPLIT*TOK*NRANK fp32

  // one fused conversion dispatch (x, W_base, lora_up, lora_down -> bf16)
  cvt_all_kernel<<<RTOT / 256, 256, 0, stream>>>(x, wb, lu, ld, Xe, Wc, Ldb);

  // down-projection: D32[z] = Xe[:, z*1024:(z+1)*1024] @ Ld^T   (split-K)
  gemm128<KSLICE, DIN, 1><<<dim3(1, TOK / 128, KSPLIT), 256, 0, stream>>>(Xe, Ldb, D32);
  // reduce + routing scale + pack into Xe extension columns
  scale_store_kernel<<<TOK * NRANK / 4 / 256, 256, 0, stream>>>(D32, rw, Xe);
  // main GEMM: out = Xe[TOK,KE] @ Wc[DOUT,KE]^T  (256x256 schedule)
  gemm256<<<dim3((TOK / 256) * (DOUT / 256)), 512, 0, stream>>>(Xe, Wc, out);
}